// Round 2
// baseline (67.619 us; speedup 1.0000x reference)
//
#include <hip/hip_runtime.h>

#define BATCH 262144
#define HIST 100
#define HIDDEN 128

// Consume one batch of 10 float4 (20 timesteps). EARLY/RECENT are
// compile-time so the window adds cost nothing in other batches.
template<bool EARLY, bool RECENT>
__device__ __forceinline__ void consume10(const float4* buf,
                                          float& sum, float& early,
                                          float& recent, float& maxd) {
    #pragma unroll
    for (int i = 0; i < 10; ++i) {
        float4 v = buf[i];
        float s2 = v.x + v.z;
        sum += s2;
        if (EARLY)  early  += s2;
        if (RECENT) recent += s2;
        maxd = fmaxf(maxd, v.x > 0.5f ? v.y : 0.0f);
        maxd = fmaxf(maxd, v.z > 0.5f ? v.w : 0.0f);
    }
}

#define LOAD10(dst, base)                          \
    _Pragma("unroll")                              \
    for (int i = 0; i < 10; ++i) dst[i] = h4[(base) + i];

// One thread per row. Streaming phase software-pipelined with two
// 10xfloat4 register buffers (10-20 loads in flight). MLP fused,
// weights via wave-uniform s_loads (unroll 2 -> 64 live W2 scalars,
// fits SGPR budget). launch_bounds(256,4): cap VGPR<=128 so we keep
// the grid's full 16 waves/CU.
__global__ __launch_bounds__(256, 4) void competence_kernel(
    const float* __restrict__ hist,
    const float* __restrict__ W1, const float* __restrict__ b1,
    const float* __restrict__ W2, const float* __restrict__ b2,
    const float* __restrict__ W3, const float* __restrict__ b3,
    float* __restrict__ out)
{
    const int row = blockIdx.x * blockDim.x + threadIdx.x;

    const float4* __restrict__ h4 =
        (const float4*)(hist + (size_t)row * (HIST * 2));

    float sum = 0.0f, early = 0.0f, recent = 0.0f, maxd = 0.0f;

    float4 bufA[10], bufB[10];
    // prologue: 20 loads in flight
    LOAD10(bufA, 0)
    LOAD10(bufB, 10)
    // steady state: consume one batch, immediately refill it
    consume10<true, false>(bufA, sum, early, recent, maxd);  // t 0..19 (early)
    LOAD10(bufA, 20)
    consume10<false, false>(bufB, sum, early, recent, maxd); // t 20..39
    LOAD10(bufB, 30)
    consume10<false, false>(bufA, sum, early, recent, maxd); // t 40..59
    LOAD10(bufA, 40)
    consume10<false, false>(bufB, sum, early, recent, maxd); // t 60..79
    consume10<false, true>(bufA, sum, early, recent, maxd);  // t 80..99 (recent)

    const float f0 = sum * 0.01f;                 // success_rate
    const float f1 = (recent - early) * 0.05f;    // improvement_trend
    const float f2 = maxd;                        // max_difficulty_handled

    float acc[32];
    #pragma unroll
    for (int k = 0; k < 32; ++k) acc[k] = b2[k];

    #pragma unroll 2
    for (int j = 0; j < HIDDEN; ++j) {
        float h = b1[j];
        h = fmaf(f0, W1[j], h);
        h = fmaf(f1, W1[HIDDEN + j], h);
        h = fmaf(f2, W1[2 * HIDDEN + j], h);
        h = fmaxf(h, 0.0f);                       // relu
        const float4* __restrict__ w2v = (const float4*)(W2 + j * 32);
        #pragma unroll
        for (int q = 0; q < 8; ++q) {
            float4 w = w2v[q];
            acc[4 * q + 0] = fmaf(h, w.x, acc[4 * q + 0]);
            acc[4 * q + 1] = fmaf(h, w.y, acc[4 * q + 1]);
            acc[4 * q + 2] = fmaf(h, w.z, acc[4 * q + 2]);
            acc[4 * q + 3] = fmaf(h, w.w, acc[4 * q + 3]);
        }
    }

    float o = b3[0];
    #pragma unroll
    for (int k = 0; k < 32; ++k)
        o = fmaf(fmaxf(acc[k], 0.0f), W3[k], o);  // relu + final dot

    out[row] = 1.0f / (1.0f + __expf(-o));        // sigmoid
}

extern "C" void kernel_launch(void* const* d_in, const int* in_sizes, int n_in,
                              void* d_out, int out_size, void* d_ws, size_t ws_size,
                              hipStream_t stream) {
    const float* hist = (const float*)d_in[0];
    const float* W1   = (const float*)d_in[1];
    const float* b1   = (const float*)d_in[2];
    const float* W2   = (const float*)d_in[3];
    const float* b2   = (const float*)d_in[4];
    const float* W3   = (const float*)d_in[5];
    const float* b3   = (const float*)d_in[6];
    float* out = (float*)d_out;

    const int threads = 256;
    const int blocks  = BATCH / threads;  // 1024 blocks = 4096 waves
    competence_kernel<<<blocks, threads, 0, stream>>>(
        hist, W1, b1, W2, b2, W3, b3, out);
}